// Round 4
// baseline (3558.109 us; speedup 1.0000x reference)
//
#include <hip/hip_runtime.h>
#include <math.h>

#define E_TOT 200000
#define NNODE 12500
#define DD 128
#define G3 384
#define NRB 20
#define TM 64            // edges per block tile
#define NTHR 256

// ---- device scratch (avoids workspace-size assumptions) ----
__device__ int d_cnt[NNODE];
__device__ int d_offs[NNODE];
__device__ int d_perm[E_TOT];
__device__ float d_scr[E_TOT * 512];   // 409.6 MB: per-edge [vv0|vv1|vv2|s1] x 128

// ---------------- kernel 0: zero the histogram --------------------------------
__global__ void zero_kernel() {
    int i = blockIdx.x * blockDim.x + threadIdx.x;
    if (i < NNODE) d_cnt[i] = 0;
}

// ---------------- kernel 1: global sum-of-squares of r + node histogram -------
__global__ void prep_kernel(const float* __restrict__ r,
                            const int* __restrict__ idx_i,
                            float* __restrict__ ws) {
    const int tid = blockIdx.x * blockDim.x + threadIdx.x;
    const int stride = gridDim.x * blockDim.x;
    const int n = E_TOT * 3;
    float acc = 0.f;
    for (int i = tid; i < n; i += stride) {
        float x = r[i];
        acc += x * x;
    }
    #pragma unroll
    for (int off = 32; off > 0; off >>= 1)
        acc += __shfl_down(acc, off, 64);
    __shared__ float wsum[4];
    int lane = threadIdx.x & 63, wid = threadIdx.x >> 6;
    if (lane == 0) wsum[wid] = acc;
    __syncthreads();
    if (threadIdx.x == 0)
        atomicAdd(ws, wsum[0] + wsum[1] + wsum[2] + wsum[3]);
    for (int e = tid; e < E_TOT; e += stride)
        atomicAdd(&d_cnt[idx_i[e]], 1);
}

// ---------------- kernel 2: exclusive prefix sum over 12500 bins --------------
__global__ void scan_kernel() {
    __shared__ int part[NTHR];
    const int per = (NNODE + NTHR - 1) / NTHR;   // 49
    const int t = threadIdx.x;
    const int lo = t * per;
    const int hi = (lo + per < NNODE) ? lo + per : NNODE;
    int sum = 0;
    for (int i = lo; i < hi; ++i) sum += d_cnt[i];
    part[t] = sum;
    __syncthreads();
    if (t == 0) {
        int acc = 0;
        for (int k = 0; k < NTHR; ++k) { int c = part[k]; part[k] = acc; acc += c; }
    }
    __syncthreads();
    int acc = part[t];
    for (int i = lo; i < hi; ++i) { int c = d_cnt[i]; d_offs[i] = acc; acc += c; }
}

// ---------------- kernel 3: scatter edge ids into node-sorted order -----------
// After this, d_offs[n] = segment END, d_cnt[n] = segment length (CSR).
__global__ void scatter_kernel(const int* __restrict__ idx_i) {
    const int tid = blockIdx.x * blockDim.x + threadIdx.x;
    const int stride = gridDim.x * blockDim.x;
    for (int e = tid; e < E_TOT; e += stride) {
        int p = atomicAdd(&d_offs[idx_i[e]], 1);
        d_perm[p] = e;
    }
}

// ---------------- kernel 4: fused MLP + gating -> dense per-edge scratch ------
// No atomics. Per sorted edge p: d_scr[p*512 + row*128 + d] = vv[row][d] (row<3),
// d_scr[p*512 + 384 + d] = s1[d]. All stores coalesced (32 consecutive lanes).
__global__ __launch_bounds__(NTHR, 3) void fused_kernel(
    const float* __restrict__ s, const float* __restrict__ r,
    const float* __restrict__ v, const float* __restrict__ W1,
    const float* __restrict__ b1, const float* __restrict__ W2,
    const float* __restrict__ b2, const float* __restrict__ Ww,
    const float* __restrict__ bw, const int* __restrict__ idx_i,
    const float* __restrict__ ws, float* __restrict__ out)
{
    __shared__ float sS[TM][DD + 4];     // 33792 B : S tile, then H
    __shared__ float sB[128 * 20];       // 10240 B : W1/W2 chunk or Ww slice
    __shared__ float sFc[TM * NRB];      // 5120 B
    __shared__ float sOrg[TM * 3];       // 768 B
    __shared__ int   sPerm[TM];          // 256 B

    const int t   = threadIdx.x;
    const int e0g = blockIdx.x * TM;

    if (t < TM) sPerm[t] = d_perm[e0g + t];
    __syncthreads();

    // ---- stage S tile (gathered by sorted edge id) ----
    #pragma unroll
    for (int u = 0; u < 8; ++u) {
        int fi   = t + NTHR * u;
        int row  = fi >> 5;
        int col4 = fi & 31;
        float4 val = reinterpret_cast<const float4*>(s)[(size_t)sPerm[row] * 32 + col4];
        *reinterpret_cast<float4*>(&sS[row][col4 * 4]) = val;
    }

    // ---- fcut / org ----
    float invgn = 1.0f / sqrtf(ws[0]);
    if (t < TM) {
        int eg = sPerm[t];
        float rx = r[eg * 3 + 0], ry = r[eg * 3 + 1], rz = r[eg * 3 + 2];
        float rn = sqrtf(rx * rx + ry * ry + rz * rz);
        sOrg[t * 3 + 0] = rx * invgn;
        sOrg[t * 3 + 1] = ry * invgn;
        sOrg[t * 3 + 2] = rz * invgn;
        const float c1 = 3.14159265358979323846f / 5.0f;
        float invrn = 1.0f / rn;
        #pragma unroll
        for (int n = 0; n < NRB; ++n) {
            float rbf = sinf((float)(n + 1) * c1 * rn) * invrn;
            sFc[t * NRB + n] = (rbf <= 5.0f) ? 0.5f * (cosf(rbf * c1) + 1.0f) : 0.0f;
        }
    }

    // ================= phase 1: H = silu(S @ W1^T + b1) =================
    const int tf  = t & 15;
    const int te1 = t >> 4;
    const int e1  = te1 * 4;
    float acc1[4][8];
    #pragma unroll
    for (int j = 0; j < 8; ++j) {
        float bias = b1[tf + 16 * j];
        #pragma unroll
        for (int i = 0; i < 4; ++i) acc1[i][j] = bias;
    }
    for (int kk = 0; kk < DD; kk += 16) {
        __syncthreads();
        {
            int f = t >> 1;
            int kb = (t & 1) * 8;
            const float4* src = reinterpret_cast<const float4*>(&W1[f * DD + kk + kb]);
            float4 v0 = src[0], v1 = src[1];
            *reinterpret_cast<float4*>(&sB[f * 20 + kb])     = v0;
            *reinterpret_cast<float4*>(&sB[f * 20 + kb + 4]) = v1;
        }
        __syncthreads();
        #pragma unroll
        for (int u = 0; u < 4; ++u) {
            float4 a[4], b[8];
            #pragma unroll
            for (int i = 0; i < 4; ++i)
                a[i] = *reinterpret_cast<const float4*>(&sS[e1 + i][kk + 4 * u]);
            #pragma unroll
            for (int j = 0; j < 8; ++j)
                b[j] = *reinterpret_cast<const float4*>(&sB[(tf + 16 * j) * 20 + 4 * u]);
            #pragma unroll
            for (int i = 0; i < 4; ++i)
                #pragma unroll
                for (int j = 0; j < 8; ++j)
                    acc1[i][j] += a[i].x * b[j].x + a[i].y * b[j].y
                                + a[i].z * b[j].z + a[i].w * b[j].w;
        }
    }
    __syncthreads();
    #pragma unroll
    for (int i = 0; i < 4; ++i)
        #pragma unroll
        for (int j = 0; j < 8; ++j) {
            float x = acc1[i][j];
            sS[e1 + i][tf + 16 * j] = x / (1.0f + expf(-x));
        }

    const int td  = t & 31;              // d lane; d = td + 32*j
    const int te2 = t >> 5;              // 0..7
    const int e2  = te2 * 8;             // 8 edges per thread-group

    // ================= pass c=1 : s1 -> scratch =================
    {
        float accs[8][4];
        #pragma unroll
        for (int j = 0; j < 4; ++j) {
            float bias = b2[DD + td + 32 * j];
            #pragma unroll
            for (int i = 0; i < 8; ++i) accs[i][j] = bias;
        }
        for (int kk = 0; kk < DD; kk += 16) {
            __syncthreads();
            #pragma unroll
            for (int u = 0; u < 2; ++u) {
                int fi = t + NTHR * u;
                int g  = fi >> 2;
                int k4 = (fi & 3) * 4;
                float4 val = *reinterpret_cast<const float4*>(
                    &W2[(size_t)(DD + g) * DD + kk + k4]);
                *reinterpret_cast<float4*>(&sB[g * 20 + k4]) = val;
            }
            __syncthreads();
            #pragma unroll
            for (int u = 0; u < 4; ++u) {
                float4 bfr[4];
                #pragma unroll
                for (int j = 0; j < 4; ++j)
                    bfr[j] = *reinterpret_cast<const float4*>(&sB[(td + 32 * j) * 20 + 4 * u]);
                #pragma unroll
                for (int i = 0; i < 8; ++i) {
                    float4 a = *reinterpret_cast<const float4*>(&sS[e2 + i][kk + 4 * u]);
                    #pragma unroll
                    for (int j = 0; j < 4; ++j)
                        accs[i][j] += a.x * bfr[j].x + a.y * bfr[j].y
                                    + a.z * bfr[j].z + a.w * bfr[j].w;
                }
            }
        }
        __syncthreads();
        #pragma unroll
        for (int u = 0; u < 10; ++u) {
            int i2 = t + NTHR * u;
            sB[i2] = Ww[DD * NRB + i2];          // Ww slice c=1
        }
        __syncthreads();
        float bwv[4];
        #pragma unroll
        for (int j = 0; j < 4; ++j) bwv[j] = bw[DD + td + 32 * j];
        #pragma unroll 1
        for (int i = 0; i < 8; ++i) {
            int el = e2 + i;
            size_t p = (size_t)(e0g + el);
            float fc[NRB];
            #pragma unroll
            for (int n4 = 0; n4 < 5; ++n4) {
                float4 f4 = *reinterpret_cast<const float4*>(&sFc[el * NRB + n4 * 4]);
                fc[n4 * 4 + 0] = f4.x; fc[n4 * 4 + 1] = f4.y;
                fc[n4 * 4 + 2] = f4.z; fc[n4 * 4 + 3] = f4.w;
            }
            #pragma unroll
            for (int j = 0; j < 4; ++j) {
                const float4* wr4 = reinterpret_cast<const float4*>(&sB[(td + 32 * j) * NRB]);
                float w = bwv[j];
                #pragma unroll
                for (int n4 = 0; n4 < 5; ++n4) {
                    float4 wv = wr4[n4];
                    w += fc[n4 * 4 + 0] * wv.x + fc[n4 * 4 + 1] * wv.y
                       + fc[n4 * 4 + 2] * wv.z + fc[n4 * 4 + 3] * wv.w;
                }
                d_scr[p * 512 + 384 + td + 32 * j] = w * accs[i][j];
            }
        }
    }

    // ================= joint pass c=0 & c=2 : vv -> scratch =================
    {
        float acc[8][8];                 // j 0..3: phi_c0 ; j 4..7: phi_c2
        #pragma unroll
        for (int j = 0; j < 4; ++j) {
            float b0 = b2[td + 32 * j];
            float bc = b2[2 * DD + td + 32 * j];
            #pragma unroll
            for (int i = 0; i < 8; ++i) { acc[i][j] = b0; acc[i][4 + j] = bc; }
        }
        for (int kk = 0; kk < DD; kk += 16) {
            // sub-stage c0
            __syncthreads();
            #pragma unroll
            for (int u = 0; u < 2; ++u) {
                int fi = t + NTHR * u;
                int g  = fi >> 2;
                int k4 = (fi & 3) * 4;
                float4 val = *reinterpret_cast<const float4*>(
                    &W2[(size_t)g * DD + kk + k4]);
                *reinterpret_cast<float4*>(&sB[g * 20 + k4]) = val;
            }
            __syncthreads();
            #pragma unroll
            for (int u = 0; u < 4; ++u) {
                float4 bfr[4];
                #pragma unroll
                for (int j = 0; j < 4; ++j)
                    bfr[j] = *reinterpret_cast<const float4*>(&sB[(td + 32 * j) * 20 + 4 * u]);
                #pragma unroll
                for (int i = 0; i < 8; ++i) {
                    float4 a = *reinterpret_cast<const float4*>(&sS[e2 + i][kk + 4 * u]);
                    #pragma unroll
                    for (int j = 0; j < 4; ++j)
                        acc[i][j] += a.x * bfr[j].x + a.y * bfr[j].y
                                   + a.z * bfr[j].z + a.w * bfr[j].w;
                }
            }
            // sub-stage c2
            __syncthreads();
            #pragma unroll
            for (int u = 0; u < 2; ++u) {
                int fi = t + NTHR * u;
                int g  = fi >> 2;
                int k4 = (fi & 3) * 4;
                float4 val = *reinterpret_cast<const float4*>(
                    &W2[(size_t)(2 * DD + g) * DD + kk + k4]);
                *reinterpret_cast<float4*>(&sB[g * 20 + k4]) = val;
            }
            __syncthreads();
            #pragma unroll
            for (int u = 0; u < 4; ++u) {
                float4 bfr[4];
                #pragma unroll
                for (int j = 0; j < 4; ++j)
                    bfr[j] = *reinterpret_cast<const float4*>(&sB[(td + 32 * j) * 20 + 4 * u]);
                #pragma unroll
                for (int i = 0; i < 8; ++i) {
                    float4 a = *reinterpret_cast<const float4*>(&sS[e2 + i][kk + 4 * u]);
                    #pragma unroll
                    for (int j = 0; j < 4; ++j)
                        acc[i][4 + j] += a.x * bfr[j].x + a.y * bfr[j].y
                                       + a.z * bfr[j].z + a.w * bfr[j].w;
                }
            }
        }
        // ---- gate c0 into registers ----
        __syncthreads();
        #pragma unroll
        for (int u = 0; u < 10; ++u) {
            int i2 = t + NTHR * u;
            sB[i2] = Ww[i2];                     // Ww slice c=0
        }
        __syncthreads();
        float bwv0[4], bwv2[4];
        #pragma unroll
        for (int j = 0; j < 4; ++j) {
            bwv0[j] = bw[td + 32 * j];
            bwv2[j] = bw[2 * DD + td + 32 * j];
        }
        float w0[8][4];
        #pragma unroll 1
        for (int i = 0; i < 8; ++i) {
            int el = e2 + i;
            float fc[NRB];
            #pragma unroll
            for (int n4 = 0; n4 < 5; ++n4) {
                float4 f4 = *reinterpret_cast<const float4*>(&sFc[el * NRB + n4 * 4]);
                fc[n4 * 4 + 0] = f4.x; fc[n4 * 4 + 1] = f4.y;
                fc[n4 * 4 + 2] = f4.z; fc[n4 * 4 + 3] = f4.w;
            }
            #pragma unroll
            for (int j = 0; j < 4; ++j) {
                const float4* wr4 = reinterpret_cast<const float4*>(&sB[(td + 32 * j) * NRB]);
                float w = bwv0[j];
                #pragma unroll
                for (int n4 = 0; n4 < 5; ++n4) {
                    float4 wv = wr4[n4];
                    w += fc[n4 * 4 + 0] * wv.x + fc[n4 * 4 + 1] * wv.y
                       + fc[n4 * 4 + 2] * wv.z + fc[n4 * 4 + 3] * wv.w;
                }
                w0[i][j] = w;
            }
        }
        // ---- gate c2 + combine + store vv ----
        __syncthreads();
        #pragma unroll
        for (int u = 0; u < 10; ++u) {
            int i2 = t + NTHR * u;
            sB[i2] = Ww[2 * DD * NRB + i2];      // Ww slice c=2
        }
        __syncthreads();
        #pragma unroll 1
        for (int i = 0; i < 8; ++i) {
            int el = e2 + i;
            size_t p = (size_t)(e0g + el);
            int eg = sPerm[el];
            float fc[NRB];
            #pragma unroll
            for (int n4 = 0; n4 < 5; ++n4) {
                float4 f4 = *reinterpret_cast<const float4*>(&sFc[el * NRB + n4 * 4]);
                fc[n4 * 4 + 0] = f4.x; fc[n4 * 4 + 1] = f4.y;
                fc[n4 * 4 + 2] = f4.z; fc[n4 * 4 + 3] = f4.w;
            }
            float o0 = sOrg[el * 3 + 0], o1 = sOrg[el * 3 + 1], o2 = sOrg[el * 3 + 2];
            const float* vrow = &v[(size_t)eg * 3 * DD];
            #pragma unroll
            for (int j = 0; j < 4; ++j) {
                const float4* wr4 = reinterpret_cast<const float4*>(&sB[(td + 32 * j) * NRB]);
                float w = bwv2[j];
                #pragma unroll
                for (int n4 = 0; n4 < 5; ++n4) {
                    float4 wv = wr4[n4];
                    w += fc[n4 * 4 + 0] * wv.x + fc[n4 * 4 + 1] * wv.y
                       + fc[n4 * 4 + 2] * wv.z + fc[n4 * 4 + 3] * wv.w;
                }
                float sp0 = w0[i][j] * acc[i][j];
                float sp2 = w * acc[i][4 + j];
                int d = td + 32 * j;
                d_scr[p * 512 +           d] = sp2 * o0 + sp0 * vrow[0 * DD + d];
                d_scr[p * 512 + 1 * 128 + d] = sp2 * o1 + sp0 * vrow[1 * DD + d];
                d_scr[p * 512 + 2 * 128 + d] = sp2 * o2 + sp0 * vrow[2 * DD + d];
            }
        }
    }
}

// ---------------- kernel 5: CSR segment-sum -> out (no atomics) ---------------
__global__ __launch_bounds__(NTHR) void reduce_kernel(float* __restrict__ out) {
    const int n = blockIdx.x;
    const int t = threadIdx.x;
    const int end = d_offs[n];
    const int beg = end - d_cnt[n];
    float a0 = 0.f, a1 = 0.f;
    for (int p = beg; p < end; ++p) {
        const float* rowp = &d_scr[(size_t)p * 512];
        a0 += rowp[t];
        a1 += rowp[256 + t];
    }
    float* out_v = out;                               // N*3*128
    float* out_s = out + (size_t)NNODE * G3;          // N*128
    out_v[(size_t)n * G3 + t] = a0;                   // slots 0..255
    if (t < 128) out_v[(size_t)n * G3 + 256 + t] = a1;  // slots 256..383
    else         out_s[(size_t)n * DD + (t - 128)] = a1; // s1 slots
}

extern "C" void kernel_launch(void* const* d_in, const int* in_sizes, int n_in,
                              void* d_out, int out_size, void* d_ws, size_t ws_size,
                              hipStream_t stream) {
    const float* s  = (const float*)d_in[0];
    const float* r  = (const float*)d_in[1];
    const float* v  = (const float*)d_in[2];
    const float* W1 = (const float*)d_in[3];
    const float* b1 = (const float*)d_in[4];
    const float* W2 = (const float*)d_in[5];
    const float* b2 = (const float*)d_in[6];
    const float* Ww = (const float*)d_in[7];
    const float* bw = (const float*)d_in[8];
    const int* idx  = (const int*)d_in[9];
    float* out = (float*)d_out;
    float* ws  = (float*)d_ws;

    hipMemsetAsync(d_out, 0, (size_t)out_size * sizeof(float), stream);
    hipMemsetAsync(d_ws, 0, sizeof(float), stream);
    zero_kernel<<<(NNODE + NTHR - 1) / NTHR, NTHR, 0, stream>>>();
    prep_kernel<<<256, NTHR, 0, stream>>>(r, idx, ws);
    scan_kernel<<<1, NTHR, 0, stream>>>();
    scatter_kernel<<<128, NTHR, 0, stream>>>(idx);
    fused_kernel<<<E_TOT / TM, NTHR, 0, stream>>>(s, r, v, W1, b1, W2, b2, Ww, bw, idx, ws, out);
    reduce_kernel<<<NNODE, NTHR, 0, stream>>>(out);
}